// Round 4
// baseline (59.120 us; speedup 1.0000x reference)
//
#include <hip/hip_runtime.h>
#include <stdint.h>

#define GLOBAL_AS __attribute__((address_space(1)))
#define LDS_AS    __attribute__((address_space(3)))

typedef __attribute__((ext_vector_type(8))) __bf16 bf16x8;
typedef __attribute__((ext_vector_type(4))) float  f32x4;

static_assert(sizeof(bf16x8) == 16, "bf16x8 must be 16B");

constexpr int N  = 4096;   // B*P rows
constexpr int DK = 512;    // feature dim

// ---------------------------------------------------------------------------
// ws layout:
//   Xb       : bf16 [4096][512]        @ 0          (4 MiB)   [dead after k_main]
//   cls      : int32[4096]             @ 4 MiB      (16 KiB)
//   partials : float4 [4096][32]       @ 4MiB+16KiB (2 MiB)  {S,P,E,W}
//   blockSums: float[256]              @ 0          (aliases dead Xb; same-stream safe)
// ---------------------------------------------------------------------------

// blocks 0..1023: fp32->bf16 convert (8 elems/thread). block 1024: build cls.
__global__ void k_convert(const float* __restrict__ X, __bf16* __restrict__ Xb,
                          const int* __restrict__ tbuf, int* __restrict__ cls) {
    if (blockIdx.x == 1024) {
        __shared__ int is64;
        const int t = threadIdx.x;          // 256 threads
        if (t == 0) is64 = 1;
        __syncthreads();
        // int64 targets => odd int32 words zero; inspect only first 1024 words (OOB-safe)
        if (tbuf[4 * t + 1] != 0 || tbuf[4 * t + 3] != 0) is64 = 0;
        __syncthreads();
        const int f = is64;
#pragma unroll
        for (int q = 0; q < 4; ++q) {
            const int ti = 4 * t + q;
            const int v = tbuf[f ? 2 * ti : ti];
            cls[4 * ti + 0] = v; cls[4 * ti + 1] = v;
            cls[4 * ti + 2] = v; cls[4 * ti + 3] = v;
        }
        return;
    }
    int idx = blockIdx.x * blockDim.x + threadIdx.x;
    const float4* s = (const float4*)X;
    float4 a = s[2 * idx + 0];
    float4 b = s[2 * idx + 1];
    bf16x8 o;
    o[0] = (__bf16)a.x; o[1] = (__bf16)a.y; o[2] = (__bf16)a.z; o[3] = (__bf16)a.w;
    o[4] = (__bf16)b.x; o[5] = (__bf16)b.y; o[6] = (__bf16)b.z; o[7] = (__bf16)b.w;
    *(bf16x8*)(Xb + 8 * idx) = o;
}

// Triangular 128x128-tile GEMM (rt >= g), 512 threads = 8 waves (2x4 grid),
// 2-phase prefetch double-buffer, XOR-swizzled LDS (pre-swizzled global src,
// linear global_load_lds dest, swizzled ds_read). Atomic-free epilogue via
// per-wave LDS slots summed in fixed order (deterministic).
// Grid = 32*33/2 = 528 blocks; LDS 77KB -> 2 blocks/CU, 16 waves/CU.
__launch_bounds__(512, 4)
__global__ void k_main(const __bf16* __restrict__ Xb, const int* __restrict__ cls,
                       float* __restrict__ partials) {
    __shared__ __align__(16) __bf16 As[2][128 * 64];   // [buf][row][k], 128B rows
    __shared__ __align__(16) __bf16 Bs[2][128 * 64];
    __shared__ float4 accR[4][128];   // [wc][row]  row stats {S,P,E,W}
    __shared__ float4 accC[2][128];   // [wr][col]  col stats
    __shared__ int rowcls[128], colcls[128];

    const int tid  = threadIdx.x;
    const int lane = tid & 63;
    const int wid  = tid >> 6;          // 0..7
    const int wr   = wid >> 2;          // 0..1 : rows wr*64..+63
    const int wc   = wid & 3;           // 0..3 : cols wc*32..+31

    // triangular decode: bid -> (rt, g), rt >= g
    const int bid = blockIdx.x;
    int rt = (int)((sqrtf(8.0f * (float)bid + 1.0f) - 1.0f) * 0.5f);
    while (((rt + 1) * (rt + 2)) / 2 <= bid) ++rt;
    while ((rt * (rt + 1)) / 2 > bid) --rt;
    const int g  = bid - (rt * (rt + 1)) / 2;
    const int i0 = rt * 128;
    const int j0 = g * 128;
    const bool offdiag = (rt != g);

    if (tid < 128) {
        rowcls[tid] = cls[i0 + tid];
        colcls[tid] = cls[j0 + tid];
    }

    f32x4 acc[4][2] = {};

    const char* xb   = (const char*)Xb;
    const int   srow = tid >> 3;                        // 0..63 staging row
    const int   skb  = ((tid & 7) ^ (srow & 7)) * 16;   // pre-swizzled source chunk
    const int   ldst = wid * 1024;                      // wave-uniform LDS offset
    const int   rA   = lane & 15;
    const int   kgrp = lane >> 4;

#define STAGE(buf, kt)                                                                         \
    {                                                                                          \
        const size_t kb0 = (size_t)(kt) * 128;                                                 \
        char* AsB = (char*)(&As[(buf)][0]);                                                    \
        char* BsB = (char*)(&Bs[(buf)][0]);                                                    \
        _Pragma("unroll")                                                                      \
        for (int t = 0; t < 2; ++t) {                                                          \
            __builtin_amdgcn_global_load_lds(                                                  \
                (const GLOBAL_AS void*)(xb + (size_t)(i0 + t * 64 + srow) * 1024 + kb0 + skb), \
                (LDS_AS void*)(AsB + t * 8192 + ldst), 16, 0, 0);                              \
            __builtin_amdgcn_global_load_lds(                                                  \
                (const GLOBAL_AS void*)(xb + (size_t)(j0 + t * 64 + srow) * 1024 + kb0 + skb), \
                (LDS_AS void*)(BsB + t * 8192 + ldst), 16, 0, 0);                              \
        }                                                                                      \
    }

    STAGE(0, 0);
    __syncthreads();                       // buf0 ready (barrier drains vmcnt)

    int cur = 0;
#pragma unroll
    for (int kt = 0; kt < DK / 64; ++kt) {
        if (kt < DK / 64 - 1) STAGE(cur ^ 1, kt + 1);   // prefetch overlaps compute
        const char* A_ = (const char*)(&As[cur][0]);
        const char* B_ = (const char*)(&Bs[cur][0]);
#pragma unroll
        for (int kk = 0; kk < 2; ++kk) {
            bf16x8 af[4];
            bf16x8 bg[2];
#pragma unroll
            for (int m = 0; m < 4; ++m) {
                const int r = wr * 64 + m * 16 + rA;
                af[m] = *(const bf16x8*)(A_ + r * 128 + (((kk * 4 + kgrp) ^ (r & 7)) * 16));
            }
#pragma unroll
            for (int n = 0; n < 2; ++n) {
                const int r = wc * 32 + n * 16 + rA;
                bg[n] = *(const bf16x8*)(B_ + r * 128 + (((kk * 4 + kgrp) ^ (r & 7)) * 16));
            }
#pragma unroll
            for (int m = 0; m < 4; ++m)
#pragma unroll
                for (int n = 0; n < 2; ++n)
                    acc[m][n] = __builtin_amdgcn_mfma_f32_16x16x32_bf16(af[m], bg[n],
                                                                        acc[m][n], 0, 0, 0);
        }
        if (kt < DK / 64 - 1) {
            __syncthreads();               // prefetch landed + all reads of cur done
            cur ^= 1;
        }
    }
#undef STAGE

    // ---- epilogue: fold acc into per-row AND per-col (S, P, E, W) ----
    // C/D: col = lane&15 (rA), row = kgrp*4 + reg  [m89-verified]
    // part(i)=i&3: row part = reg r, col part = rA&3 (all tile bases %4==0)
    const int pj = rA & 3;
    int cj[2];
#pragma unroll
    for (int n = 0; n < 2; ++n) cj[n] = colcls[wc * 32 + n * 16 + rA];
    float cS[2] = {0.f, 0.f}, cP[2] = {0.f, 0.f}, cE[2] = {0.f, 0.f}, cW[2] = {0.f, 0.f};

#pragma unroll
    for (int m = 0; m < 4; ++m) {
        const int rbase = wr * 64 + m * 16 + kgrp * 4;
        int ci[4];
#pragma unroll
        for (int r = 0; r < 4; ++r) ci[r] = rowcls[rbase + r];
        float sS[4] = {0.f, 0.f, 0.f, 0.f};
        float sP[4] = {0.f, 0.f, 0.f, 0.f};
        float sE[4] = {0.f, 0.f, 0.f, 0.f};
        float sW[4] = {0.f, 0.f, 0.f, 0.f};
#pragma unroll
        for (int n = 0; n < 2; ++n) {
#pragma unroll
            for (int r = 0; r < 4; ++r) {
                const float p  = acc[m][n][r];
                const float ep = __expf(p);
                const bool sc = (ci[r] == cj[n]);
                const bool sp = (r == pj);
                if (!sc && !sp) { sS[r] += ep; cS[n] += ep; }   // dadc
                const float w = (!sc && sp) ? 2.f : ((sc && !sp) ? 1.f : 0.f);
                sP[r] += w * p;  sE[r] += w * ep;  sW[r] += w;
                cP[n] += w * p;  cE[n] += w * ep;  cW[n] += w;
            }
        }
#pragma unroll
        for (int r = 0; r < 4; ++r) {
            float vS = sS[r], vP = sP[r], vE = sE[r], vW = sW[r];
#pragma unroll
            for (int off = 1; off < 16; off <<= 1) {   // reduce across rA (cols)
                vS += __shfl_xor(vS, off);
                vP += __shfl_xor(vP, off);
                vE += __shfl_xor(vE, off);
                vW += __shfl_xor(vW, off);
            }
            if (rA == 0) accR[wc][rbase + r] = make_float4(vS, vP, vE, vW);
        }
    }

    {   // col stats: reduce across kgrp (rows); unique LDS slot per (wr, col)
#pragma unroll
        for (int n = 0; n < 2; ++n) {
            float vS = cS[n], vP = cP[n], vE = cE[n], vW = cW[n];
            vS += __shfl_xor(vS, 16); vS += __shfl_xor(vS, 32);
            vP += __shfl_xor(vP, 16); vP += __shfl_xor(vP, 32);
            vE += __shfl_xor(vE, 16); vE += __shfl_xor(vE, 32);
            vW += __shfl_xor(vW, 16); vW += __shfl_xor(vW, 32);
            if (kgrp == 0) accC[wr][wc * 32 + n * 16 + rA] = make_float4(vS, vP, vE, vW);
        }
    }

    __syncthreads();
    if (tid < 128) {   // fixed-order sums => deterministic
        float4 a0 = accR[0][tid], a1 = accR[1][tid], a2 = accR[2][tid], a3 = accR[3][tid];
        float4 o = make_float4(a0.x + a1.x + a2.x + a3.x, a0.y + a1.y + a2.y + a3.y,
                               a0.z + a1.z + a2.z + a3.z, a0.w + a1.w + a2.w + a3.w);
        ((float4*)partials)[(size_t)(i0 + tid) * 32 + g] = o;
        if (offdiag) {
            float4 c0 = accC[0][tid], c1 = accC[1][tid];
            float4 oc = make_float4(c0.x + c1.x, c0.y + c1.y, c0.z + c1.z, c0.w + c1.w);
            ((float4*)partials)[(size_t)(j0 + tid) * 32 + rt] = oc;
        }
    }
}

// Stage 1: 256 blocks x 256 threads; 16 threads per row; 16 rows per block.
__global__ void k_rowloss(const float* __restrict__ partials, float* __restrict__ blockSums) {
    __shared__ float red[16];
    const int tid = threadIdx.x;
    const int sub = tid & 15;
    const int row = blockIdx.x * 16 + (tid >> 4);

    const float4* p = ((const float4*)partials) + (size_t)row * 32;
    float4 a = p[sub];
    float4 b = p[sub + 16];
    float S = a.x + b.x, P = a.y + b.y, E = a.z + b.z, W = a.w + b.w;
#pragma unroll
    for (int off = 1; off < 16; off <<= 1) {
        S += __shfl_xor(S, off);
        P += __shfl_xor(P, off);
        E += __shfl_xor(E, off);
        W += __shfl_xor(W, off);
    }
    if (sub == 0) red[tid >> 4] = W * logf(S) - P + E / S;
    __syncthreads();
    if (tid == 0) {
        float s = 0.f;
#pragma unroll
        for (int r = 0; r < 16; ++r) s += red[r];
        blockSums[blockIdx.x] = s;
    }
}

__global__ void k_final2(const float* __restrict__ blockSums, float* __restrict__ out) {
    const int t = threadIdx.x;           // 64 threads
    float v = blockSums[t] + blockSums[t + 64] + blockSums[t + 128] + blockSums[t + 192];
#pragma unroll
    for (int off = 1; off < 64; off <<= 1) v += __shfl_xor(v, off);
    if (t == 0) out[0] = v / (float)N;
}

extern "C" void kernel_launch(void* const* d_in, const int* in_sizes, int n_in,
                              void* d_out, int out_size, void* d_ws, size_t ws_size,
                              hipStream_t stream) {
    const float* X = (const float*)d_in[0];
    const int*   T = (const int*)d_in[1];
    float* out = (float*)d_out;

    char* ws = (char*)d_ws;
    __bf16* Xb     = (__bf16*)ws;
    int*    cls    = (int*)(ws + (size_t)4 * 1024 * 1024);
    float*  parts  = (float*)(ws + (size_t)4 * 1024 * 1024 + 16 * 1024);
    float*  bsums  = (float*)ws;   // aliases Xb (dead after k_main; same-stream ordering)

    hipLaunchKernelGGL(k_convert, dim3(1025), dim3(256), 0, stream, X, Xb, T, cls);
    hipLaunchKernelGGL(k_main,    dim3(528),  dim3(512), 0, stream, Xb, cls, parts);
    hipLaunchKernelGGL(k_rowloss, dim3(256),  dim3(256), 0, stream, parts, bsums);
    hipLaunchKernelGGL(k_final2,  dim3(1),    dim3(64),  0, stream, bsums, out);
}

// Round 5
// 47.612 us; speedup vs baseline: 1.2417x; 1.2417x over previous
//
#include <hip/hip_runtime.h>
#include <stdint.h>

#define GLOBAL_AS __attribute__((address_space(1)))
#define LDS_AS    __attribute__((address_space(3)))

typedef __attribute__((ext_vector_type(8))) __bf16 bf16x8;
typedef __attribute__((ext_vector_type(4))) float  f32x4;

static_assert(sizeof(bf16x8) == 16, "bf16x8 must be 16B");

constexpr int N  = 4096;   // B*P rows
constexpr int DK = 512;    // feature dim

// ---------------------------------------------------------------------------
// ws layout:
//   Xb       : bf16 [4096][512]        @ 0          (4 MiB)   [dead after k_main]
//   cls      : int32[4096]             @ 4 MiB      (16 KiB)
//   partials : float4 [4096][32]       @ 4MiB+16KiB (2 MiB)  {S,P,E,W}
//   blockSums: float[256]              @ 0          (aliases dead Xb; same-stream safe)
// ---------------------------------------------------------------------------

// blocks 0..1023: fp32->bf16 convert (8 elems/thread). block 1024: build cls.
__global__ void k_convert(const float* __restrict__ X, __bf16* __restrict__ Xb,
                          const int* __restrict__ tbuf, int* __restrict__ cls) {
    if (blockIdx.x == 1024) {
        __shared__ int is64;
        const int t = threadIdx.x;          // 256 threads
        if (t == 0) is64 = 1;
        __syncthreads();
        // int64 targets => odd int32 words zero; inspect only first 1024 words (OOB-safe)
        if (tbuf[4 * t + 1] != 0 || tbuf[4 * t + 3] != 0) is64 = 0;
        __syncthreads();
        const int f = is64;
#pragma unroll
        for (int q = 0; q < 4; ++q) {
            const int ti = 4 * t + q;
            const int v = tbuf[f ? 2 * ti : ti];
            cls[4 * ti + 0] = v; cls[4 * ti + 1] = v;
            cls[4 * ti + 2] = v; cls[4 * ti + 3] = v;
        }
        return;
    }
    int idx = blockIdx.x * blockDim.x + threadIdx.x;
    const float4* s = (const float4*)X;
    float4 a = s[2 * idx + 0];
    float4 b = s[2 * idx + 1];
    bf16x8 o;
    o[0] = (__bf16)a.x; o[1] = (__bf16)a.y; o[2] = (__bf16)a.z; o[3] = (__bf16)a.w;
    o[4] = (__bf16)b.x; o[5] = (__bf16)b.y; o[6] = (__bf16)b.z; o[7] = (__bf16)b.w;
    *(bf16x8*)(Xb + 8 * idx) = o;
}

// Triangular 128x128-tile GEMM (rt >= g), 512 threads = 8 waves (2x4 grid),
// 2-phase prefetch double-buffer, XOR-swizzled LDS, XCD-aware bid swizzle.
// SWAPPED MFMA operands: acc = mfma(B_frag, A_frag) => C layout i=rA, j=kgrp*4+reg,
// making row-stat reduction the cheap (2-shfl) axis. Atomic-free deterministic
// epilogue. Grid = 32*33/2 = 528 blocks; LDS 77KB -> 2 blocks/CU, 16 waves/CU.
__launch_bounds__(512, 4)
__global__ void k_main(const __bf16* __restrict__ Xb, const int* __restrict__ cls,
                       float* __restrict__ partials) {
    __shared__ __align__(16) __bf16 As[2][128 * 64];   // [buf][row][k], 128B rows
    __shared__ __align__(16) __bf16 Bs[2][128 * 64];
    __shared__ float4 accR[4][128];   // [wc][row]  row stats {S,P,E,W}
    __shared__ float4 accC[2][128];   // [wr][col]  col stats
    __shared__ int rowcls[128], colcls[128];

    const int tid  = threadIdx.x;
    const int lane = tid & 63;
    const int wid  = tid >> 6;          // 0..7
    const int wr   = wid >> 2;          // 0..1 : rows wr*64..+63
    const int wc   = wid & 3;           // 0..3 : cols wc*32..+31

    // XCD-aware bijective swizzle (528 = 8 * 66): same-rt blocks share an XCD L2
    const int bid = (blockIdx.x & 7) * 66 + (blockIdx.x >> 3);
    // triangular decode: bid -> (rt, g), rt >= g
    int rt = (int)((sqrtf(8.0f * (float)bid + 1.0f) - 1.0f) * 0.5f);
    while (((rt + 1) * (rt + 2)) / 2 <= bid) ++rt;
    while ((rt * (rt + 1)) / 2 > bid) --rt;
    const int g  = bid - (rt * (rt + 1)) / 2;
    const int i0 = rt * 128;
    const int j0 = g * 128;
    const bool offdiag = (rt != g);

    if (tid < 128) {
        rowcls[tid] = cls[i0 + tid];
        colcls[tid] = cls[j0 + tid];
    }

    f32x4 acc[4][2] = {};

    const char* xb   = (const char*)Xb;
    const int   srow = tid >> 3;                        // 0..63 staging row
    const int   skb  = ((tid & 7) ^ (srow & 7)) * 16;   // pre-swizzled source chunk
    const int   ldst = wid * 1024;                      // wave-uniform LDS offset
    const int   rA   = lane & 15;
    const int   kgrp = lane >> 4;

#define STAGE(buf, kt)                                                                         \
    {                                                                                          \
        const size_t kb0 = (size_t)(kt) * 128;                                                 \
        char* AsB = (char*)(&As[(buf)][0]);                                                    \
        char* BsB = (char*)(&Bs[(buf)][0]);                                                    \
        _Pragma("unroll")                                                                      \
        for (int t = 0; t < 2; ++t) {                                                          \
            __builtin_amdgcn_global_load_lds(                                                  \
                (const GLOBAL_AS void*)(xb + (size_t)(i0 + t * 64 + srow) * 1024 + kb0 + skb), \
                (LDS_AS void*)(AsB + t * 8192 + ldst), 16, 0, 0);                              \
            __builtin_amdgcn_global_load_lds(                                                  \
                (const GLOBAL_AS void*)(xb + (size_t)(j0 + t * 64 + srow) * 1024 + kb0 + skb), \
                (LDS_AS void*)(BsB + t * 8192 + ldst), 16, 0, 0);                              \
        }                                                                                      \
    }

    STAGE(0, 0);
    __syncthreads();                       // buf0 ready (barrier drains vmcnt)

    int cur = 0;
#pragma unroll
    for (int kt = 0; kt < DK / 64; ++kt) {
        if (kt < DK / 64 - 1) STAGE(cur ^ 1, kt + 1);   // prefetch overlaps compute
        const char* A_ = (const char*)(&As[cur][0]);
        const char* B_ = (const char*)(&Bs[cur][0]);
#pragma unroll
        for (int kk = 0; kk < 2; ++kk) {
            bf16x8 af[4];
            bf16x8 bg[2];
#pragma unroll
            for (int m = 0; m < 4; ++m) {
                const int r = wr * 64 + m * 16 + rA;
                af[m] = *(const bf16x8*)(A_ + r * 128 + (((kk * 4 + kgrp) ^ (r & 7)) * 16));
            }
#pragma unroll
            for (int n = 0; n < 2; ++n) {
                const int r = wc * 32 + n * 16 + rA;
                bg[n] = *(const bf16x8*)(B_ + r * 128 + (((kk * 4 + kgrp) ^ (r & 7)) * 16));
            }
            // SWAPPED operands: D[j][i] = sum_k B[j,k]*A[i,k] = p(i,j)
#pragma unroll
            for (int m = 0; m < 4; ++m)
#pragma unroll
                for (int n = 0; n < 2; ++n)
                    acc[m][n] = __builtin_amdgcn_mfma_f32_16x16x32_bf16(bg[n], af[m],
                                                                        acc[m][n], 0, 0, 0);
        }
        if (kt < DK / 64 - 1) {
            __syncthreads();               // prefetch landed + all reads of cur done
            cur ^= 1;
        }
    }
#undef STAGE

    // ---- epilogue (swapped layout): p(i,j) at i = wr*64+m*16+rA,
    //      j = wc*32+n*16+kgrp*4+r.  part(i) = rA&3, part(j) = r.
    const int pi = rA & 3;
    int ci[4];
#pragma unroll
    for (int m = 0; m < 4; ++m) ci[m] = rowcls[wr * 64 + m * 16 + rA];

    float rS[4] = {0.f, 0.f, 0.f, 0.f};
    float rP[4] = {0.f, 0.f, 0.f, 0.f};
    float rE[4] = {0.f, 0.f, 0.f, 0.f};
    float rW[4] = {0.f, 0.f, 0.f, 0.f};

#pragma unroll
    for (int n = 0; n < 2; ++n) {
#pragma unroll
        for (int r = 0; r < 4; ++r) {
            const int cj = colcls[wc * 32 + n * 16 + kgrp * 4 + r];
            float cS = 0.f, cP = 0.f, cE = 0.f, cW = 0.f;   // transient col stats
#pragma unroll
            for (int m = 0; m < 4; ++m) {
                const float p  = acc[m][n][r];
                const float ep = __expf(p);
                const bool sc = (ci[m] == cj);
                const bool sp = (pi == r);
                if (!sc && !sp) { rS[m] += ep; cS += ep; }   // dadc
                const float w = (!sc && sp) ? 2.f : ((sc && !sp) ? 1.f : 0.f);
                rP[m] += w * p;  rE[m] += w * ep;  rW[m] += w;
                cP += w * p;     cE += w * ep;     cW += w;
            }
            if (offdiag) {   // reduce over i-lanes (rA axis), write per-col slot
#pragma unroll
                for (int off = 1; off < 16; off <<= 1) {
                    cS += __shfl_xor(cS, off);
                    cP += __shfl_xor(cP, off);
                    cE += __shfl_xor(cE, off);
                    cW += __shfl_xor(cW, off);
                }
                if (rA == 0)
                    accC[wr][wc * 32 + n * 16 + kgrp * 4 + r] = make_float4(cS, cP, cE, cW);
            }
        }
    }
    // row stats: reduce over j-lanes (kgrp axis): 2 shfl steps per value
#pragma unroll
    for (int m = 0; m < 4; ++m) {
        float vS = rS[m], vP = rP[m], vE = rE[m], vW = rW[m];
        vS += __shfl_xor(vS, 16); vS += __shfl_xor(vS, 32);
        vP += __shfl_xor(vP, 16); vP += __shfl_xor(vP, 32);
        vE += __shfl_xor(vE, 16); vE += __shfl_xor(vE, 32);
        vW += __shfl_xor(vW, 16); vW += __shfl_xor(vW, 32);
        if (kgrp == 0) accR[wc][wr * 64 + m * 16 + rA] = make_float4(vS, vP, vE, vW);
    }

    __syncthreads();
    if (tid < 128) {   // fixed-order sums => deterministic
        float4 a0 = accR[0][tid], a1 = accR[1][tid], a2 = accR[2][tid], a3 = accR[3][tid];
        float4 o = make_float4(a0.x + a1.x + a2.x + a3.x, a0.y + a1.y + a2.y + a3.y,
                               a0.z + a1.z + a2.z + a3.z, a0.w + a1.w + a2.w + a3.w);
        ((float4*)partials)[(size_t)(i0 + tid) * 32 + g] = o;
        if (offdiag) {
            float4 c0 = accC[0][tid], c1 = accC[1][tid];
            float4 oc = make_float4(c0.x + c1.x, c0.y + c1.y, c0.z + c1.z, c0.w + c1.w);
            ((float4*)partials)[(size_t)(j0 + tid) * 32 + rt] = oc;
        }
    }
}

// Stage 1: 256 blocks x 256 threads; 16 threads per row; 16 rows per block.
__global__ void k_rowloss(const float* __restrict__ partials, float* __restrict__ blockSums) {
    __shared__ float red[16];
    const int tid = threadIdx.x;
    const int sub = tid & 15;
    const int row = blockIdx.x * 16 + (tid >> 4);

    const float4* p = ((const float4*)partials) + (size_t)row * 32;
    float4 a = p[sub];
    float4 b = p[sub + 16];
    float S = a.x + b.x, P = a.y + b.y, E = a.z + b.z, W = a.w + b.w;
#pragma unroll
    for (int off = 1; off < 16; off <<= 1) {
        S += __shfl_xor(S, off);
        P += __shfl_xor(P, off);
        E += __shfl_xor(E, off);
        W += __shfl_xor(W, off);
    }
    if (sub == 0) red[tid >> 4] = W * logf(S) - P + E / S;
    __syncthreads();
    if (tid == 0) {
        float s = 0.f;
#pragma unroll
        for (int r = 0; r < 16; ++r) s += red[r];
        blockSums[blockIdx.x] = s;
    }
}

__global__ void k_final2(const float* __restrict__ blockSums, float* __restrict__ out) {
    const int t = threadIdx.x;           // 64 threads
    float v = blockSums[t] + blockSums[t + 64] + blockSums[t + 128] + blockSums[t + 192];
#pragma unroll
    for (int off = 1; off < 64; off <<= 1) v += __shfl_xor(v, off);
    if (t == 0) out[0] = v / (float)N;
}

extern "C" void kernel_launch(void* const* d_in, const int* in_sizes, int n_in,
                              void* d_out, int out_size, void* d_ws, size_t ws_size,
                              hipStream_t stream) {
    const float* X = (const float*)d_in[0];
    const int*   T = (const int*)d_in[1];
    float* out = (float*)d_out;

    char* ws = (char*)d_ws;
    __bf16* Xb     = (__bf16*)ws;
    int*    cls    = (int*)(ws + (size_t)4 * 1024 * 1024);
    float*  parts  = (float*)(ws + (size_t)4 * 1024 * 1024 + 16 * 1024);
    float*  bsums  = (float*)ws;   // aliases Xb (dead after k_main; same-stream ordering)

    hipLaunchKernelGGL(k_convert, dim3(1025), dim3(256), 0, stream, X, Xb, T, cls);
    hipLaunchKernelGGL(k_main,    dim3(528),  dim3(512), 0, stream, Xb, cls, parts);
    hipLaunchKernelGGL(k_rowloss, dim3(256),  dim3(256), 0, stream, parts, bsums);
    hipLaunchKernelGGL(k_final2,  dim3(1),    dim3(64),  0, stream, bsums, out);
}